// Round 2
// baseline (32.977 us; speedup 1.0000x reference)
//
#include <hip/hip_runtime.h>
#include <math.h>

#define THREADS    256
#define EPB        32      // elements per block
#define NI         9
#define NT         17
#define DEPTH      8

#define MAG_MAX    1e28f
#define MAG_MIN    1e-12f
#define LOG_LIM    100.0f

#define CH_DW      2560    // dwords per digit chunk = 256 slots * 10
#define NCHUNK     9       // 2304 slots / 256

typedef __attribute__((address_space(1))) const unsigned char gconst_byte;
typedef __attribute__((address_space(3))) unsigned char lds_byte;

__device__ __forceinline__ void gl_lds16(const float* g, float* l) {
    __builtin_amdgcn_global_load_lds((gconst_byte*)(const void*)g,
                                     (lds_byte*)(void*)l, 16, 0, 0);
}
__device__ __forceinline__ void gl_lds4(const float* g, float* l) {
    __builtin_amdgcn_global_load_lds((gconst_byte*)(const void*)g,
                                     (lds_byte*)(void*)l, 4, 0, 0);
}

// one chunk = 2560 dwords; wave w owns dwords [w*640, (w+1)*640)
// 2 x 16B-granule instrs (1 KB each) + 2 x 4B-granule instrs (256 B each) = 4 ops/wave
__device__ __forceinline__ void issue_chunk(const float* Dg, float* lbuf,
                                            int c, int w, int lane) {
    const float* gb = Dg + c * CH_DW + w * 640;
    float* lb = lbuf + w * 640;
    gl_lds16(gb + lane * 4,        lb);
    gl_lds16(gb + 256 + lane * 4,  lb + 256);
    gl_lds4 (gb + 512 + lane,      lb + 512);
    gl_lds4 (gb + 576 + lane,      lb + 576);
}

__device__ __forceinline__ float tanh_fast(float x) {
    float e = __expf(2.0f * x);
    return 1.0f - 2.0f / (e + 1.0f);
}

__global__ __launch_bounds__(THREADS, 3)
void dag_exec_kernel(const float* __restrict__ dl,   // [NE,9,8,10]
                     const float* __restrict__ vsg,  // [NE,17]
                     const float* __restrict__ Og,   // [NE,8,17]
                     const float* __restrict__ Gg,   // [NE,8]
                     float* __restrict__ out)        // [NE]
{
    __shared__ float s_dl[2 * CH_DW];      // 20 KB double-buffered digit staging (linear)
    __shared__ float s_slot[EPB * 73];     // expected*power per (elem, node*8+d)
    __shared__ float s_O[EPB * 137];       // padded, odd stride -> conflict-free phase-2 reads
    __shared__ float s_vs[EPB * NT];
    __shared__ float s_G[EPB * 9];

    const int tid  = threadIdx.x;
    const int lane = tid & 63;
    const int w    = tid >> 6;
    const long e0  = (long)blockIdx.x * EPB;
    const float* Dg = dl + e0 * 720;

    // ---- issue first two digit chunks (fully coalesced global_load_lds) ----
    issue_chunk(Dg, s_dl,         0, w, lane);
    issue_chunk(Dg, s_dl + CH_DW, 1, w, lane);
    asm volatile("" ::: "memory");

    // ---- prologue: reg-stage O (padded 137), V_sign, G ----
    {
        const float* Ob = Og + e0 * 136;
        #pragma unroll
        for (int k = 0; k < 5; ++k) {
            int idx = tid + k * 256;               // float4 index, 0..1087
            if (idx < 1088) {
                float4 v = *(const float4*)(Ob + idx * 4);
                int f = idx * 4;
                int el = f / 136, rem = f - el * 136;   // 4 dwords never cross element
                float* dst = &s_O[el * 137 + rem];
                dst[0] = v.x; dst[1] = v.y; dst[2] = v.z; dst[3] = v.w;
            }
        }
        const float* Vb = vsg + e0 * NT;
        s_vs[tid]       = Vb[tid];
        s_vs[tid + 256] = Vb[tid + 256];
        if (tid < 32) s_vs[tid + 512] = Vb[tid + 512];
        int el = tid >> 3, rem = tid & 7;
        s_G[el * 9 + rem] = Gg[e0 * 8 + tid];
    }
    asm volatile("" ::: "memory");

    // place-value power for this thread's digit position (constant across chunks)
    const int dpos = tid & 7;
    const float powv = (dpos == 0) ? 1000.0f : (dpos == 1) ? 100.0f : (dpos == 2) ? 10.0f :
                       (dpos == 3) ? 1.0f    : (dpos == 4) ? 0.1f   : (dpos == 5) ? 0.01f :
                       (dpos == 6) ? 0.001f  : 0.0001f;

    // ---- phase 1: 9 chunks, wave-local double-buffered pipeline, no barriers ----
    #pragma unroll
    for (int c = 0; c < NCHUNK; ++c) {
        // wait for chunk c (this wave's 4 ops); chunk c+1's 4 ops may stay in flight
        if (c < NCHUNK - 1) { asm volatile("s_waitcnt vmcnt(4)" ::: "memory"); }
        else                { asm volatile("s_waitcnt vmcnt(0)" ::: "memory"); }

        const float* p = s_dl + (c & 1) * CH_DW + tid * 10;   // own-wave region only
        float2 a0 = *(const float2*)(p + 0);
        float2 a1 = *(const float2*)(p + 2);
        float2 a2 = *(const float2*)(p + 4);
        float2 a3 = *(const float2*)(p + 6);
        float2 a4 = *(const float2*)(p + 8);
        float x0 = a0.x, x1 = a0.y, x2 = a1.x, x3 = a1.y, x4 = a2.x;
        float x5 = a2.y, x6 = a3.x, x7 = a3.y, x8 = a4.x, x9 = a4.y;
        float m = fmaxf(x0, x1);
        m = fmaxf(m, x2); m = fmaxf(m, x3); m = fmaxf(m, x4);
        m = fmaxf(m, x5); m = fmaxf(m, x6); m = fmaxf(m, x7);
        m = fmaxf(m, x8); m = fmaxf(m, x9);
        float e0v = __expf((x0 - m) * 100.0f);
        float e1v = __expf((x1 - m) * 100.0f);
        float e2v = __expf((x2 - m) * 100.0f);
        float e3v = __expf((x3 - m) * 100.0f);
        float e4v = __expf((x4 - m) * 100.0f);
        float e5v = __expf((x5 - m) * 100.0f);
        float e6v = __expf((x6 - m) * 100.0f);
        float e7v = __expf((x7 - m) * 100.0f);
        float e8v = __expf((x8 - m) * 100.0f);
        float e9v = __expf((x9 - m) * 100.0f);
        float den = e0v + e1v + e2v + e3v + e4v + e5v + e6v + e7v + e8v + e9v;
        float num = e1v + e2v * 2.0f + e3v * 3.0f + e4v * 4.0f +
                    e5v * 5.0f + e6v * 6.0f + e7v * 7.0f + e8v * 8.0f + e9v * 9.0f;
        float expected = num / den;

        int s = c * 256 + tid;
        int el = s / 72, rem = s - el * 72;
        s_slot[el * 73 + rem] = expected * powv;

        if (c + 2 < NCHUNK) {
            asm volatile("" ::: "memory");
            issue_chunk(Dg, s_dl + (c & 1) * CH_DW, c + 2, w, lane);
        }
    }

    // all s_slot / s_O / s_vs / s_G writes must be visible to wave 0
    asm volatile("s_waitcnt lgkmcnt(0)" ::: "memory");
    __builtin_amdgcn_s_barrier();

    // ---- phase 2: DAG, one thread per element ----
    if (tid < EPB) {
        float vmag[NT], sgn[NT], logm[NT], sv[NT];
        #pragma unroll
        for (int n = 0; n < NI; ++n) {
            float v = 0.0f;
            #pragma unroll
            for (int d = 0; d < 8; ++d) v += s_slot[tid * 73 + n * 8 + d];
            v = fminf(fmaxf(v, MAG_MIN), MAG_MAX);
            vmag[n] = v;
            sgn[n]  = s_vs[tid * NT + n];
            logm[n] = logf(v);
            sv[n]   = sgn[n] * v;
        }
        #pragma unroll
        for (int n = NI; n < NT; ++n) {
            vmag[n] = 0.0f; sgn[n] = 0.0f;
            logm[n] = logf(MAG_MIN);
            sv[n]   = 0.0f;
        }

        #pragma unroll
        for (int step = 0; step < DEPTH; ++step) {
            const int valid = NI + step;
            float g  = s_G[tid * 9 + step];
            float og = 1.0f - g;
            float R = 0.0f;
            float prod = 1.0f;
            #pragma unroll
            for (int n = 0; n < NT; ++n) {
                if (n < valid) {
                    float o = s_O[tid * 137 + step * 17 + n];
                    float mixed = logm[n] * og + sv[n] * g;
                    R += o * mixed;
                    float wgt = sgn[n] * fabsf(o) * 2.0f + 1.0f;
                    prod *= wgt;
                }
            }
            float linear_sign = tanh_fast(R * 10000.0f);
            float log_sign    = tanh_fast(prod * 10000.0f);
            float s_new = g * linear_sign + og * log_sign;
            float linear_mag  = fminf(fabsf(R), MAG_MAX);
            float Rc = fminf(fmaxf(R, -LOG_LIM), LOG_LIM);
            float log_mag_res = expf(Rc);
            float m_new = g * linear_mag + og * log_mag_res;
            m_new = fminf(fmaxf(m_new, MAG_MIN), MAG_MAX);
            s_new = fminf(fmaxf(s_new, -1.0f), 1.0f);
            vmag[valid] = m_new;
            sgn[valid]  = s_new;
            logm[valid] = logf(m_new);
            sv[valid]   = s_new * m_new;
        }
        out[e0 + tid] = sgn[NT - 1] * vmag[NT - 1];
    }
}

extern "C" void kernel_launch(void* const* d_in, const int* in_sizes, int n_in,
                              void* d_out, int out_size, void* d_ws, size_t ws_size,
                              hipStream_t stream) {
    const float* dl  = (const float*)d_in[0];   // digit_logits [B,T,9,8,10]
    const float* vsg = (const float*)d_in[1];   // V_sign       [B,T,17]
    const float* Og  = (const float*)d_in[2];   // O            [B,T,8,17]
    const float* Gg  = (const float*)d_in[3];   // G            [B,T,8]
    float* out = (float*)d_out;

    const int ne = out_size;                    // 32768
    const int blocks = ne / EPB;                // 1024
    dag_exec_kernel<<<blocks, THREADS, 0, stream>>>(dl, vsg, Og, Gg, out);
}

// Round 3
// 26.847 us; speedup vs baseline: 1.2283x; 1.2283x over previous
//
#include <hip/hip_runtime.h>
#include <math.h>

#define THREADS    256
#define EPB        32      // elements per block
#define NI         9
#define NT         17
#define DEPTH      8

#define MAG_MAX    1e28f
#define MAG_MIN    1e-12f
#define LOG_LIM    100.0f

typedef __attribute__((address_space(1))) const unsigned char gconst_byte;
typedef __attribute__((address_space(3))) unsigned char lds_byte;

__device__ __forceinline__ void gl_lds16(const float* g, float* l) {
    __builtin_amdgcn_global_load_lds((gconst_byte*)(const void*)g,
                                     (lds_byte*)(void*)l, 16, 0, 0);
}

__device__ __forceinline__ float tanh_fast(float x) {
    float e = __expf(2.0f * x);
    return 1.0f - 2.0f / (e + 1.0f);
}

__global__ __launch_bounds__(THREADS, 5)
void dag_exec_kernel(const float* __restrict__ dl,   // [NE,9,8,10]
                     const float* __restrict__ vsg,  // [NE,17]
                     const float* __restrict__ Og,   // [NE,8,17]
                     const float* __restrict__ Gg,   // [NE,8]
                     float* __restrict__ out)        // [NE]
{
    __shared__ float s_dl[2560];        // 10 KB wave-local digit buffer (640 dw/wave)
    __shared__ float s_init[EPB * 9];   // per-(elem,node) digit sums
    __shared__ float s_O[EPB * 136];    // linear — global_load_lds destination
    __shared__ float s_vs[EPB * NT];
    __shared__ float s_G[EPB * 9];

    const int tid  = threadIdx.x;
    const int lane = tid & 63;
    const int w    = tid >> 6;
    const long e0  = (long)blockIdx.x * EPB;

    const float* Dg = dl + e0 * 720;
    const float* gw = Dg + w * 640;        // this wave's slice; chunk c at +c*2560
    float* lb = s_dl + w * 640;

    // ---- chunk 0 -> regs (fully coalesced) ----
    float4 r0 = *(const float4*)(gw + lane * 4);
    float4 r1 = *(const float4*)(gw + 256 + lane * 4);
    float2 r2 = *(const float2*)(gw + 512 + lane * 2);

    // ---- O -> LDS direct, coalesced width-16 global_load_lds (17 instrs total) ----
    {
        const float* Ob = Og + e0 * 136;
        #pragma unroll
        for (int k = 0; k < 4; ++k) {
            int i = w + k * 4;                       // wave-uniform LDS base
            gl_lds16(Ob + i * 256 + lane * 4, s_O + i * 256);
        }
        if (w == 0)
            gl_lds16(Ob + 16 * 256 + lane * 4, s_O + 16 * 256);
    }
    // ---- V_sign, G (small, coalesced) ----
    {
        const float* Vb = vsg + e0 * NT;
        s_vs[tid]       = Vb[tid];
        s_vs[tid + 256] = Vb[tid + 256];
        if (tid < 32) s_vs[tid + 512] = Vb[tid + 512];
        s_G[(tid >> 3) * 9 + (tid & 7)] = Gg[e0 * 8 + tid];
    }

    // ---- store chunk 0 into LDS (wave-local) ----
    *(float4*)(lb + lane * 4)       = r0;
    *(float4*)(lb + 256 + lane * 4) = r1;
    *(float2*)(lb + 512 + lane * 2) = r2;

    const int dpos = tid & 7;
    const float powv = (dpos == 0) ? 1000.0f : (dpos == 1) ? 100.0f : (dpos == 2) ? 10.0f :
                       (dpos == 3) ? 1.0f    : (dpos == 4) ? 0.1f   : (dpos == 5) ? 0.01f :
                       (dpos == 6) ? 0.001f  : 0.0001f;

    // ---- phase 1: 9 chunks, wave-local single-buffer pipeline, no barriers ----
    #pragma unroll
    for (int c = 0; c < 9; ++c) {
        float4 n0, n1; float2 n2;
        if (c < 8) {                                  // issue next chunk early
            const float* gn = gw + (c + 1) * 2560;
            n0 = *(const float4*)(gn + lane * 4);
            n1 = *(const float4*)(gn + 256 + lane * 4);
            n2 = *(const float2*)(gn + 512 + lane * 2);
        }

        const float* p = lb + lane * 10;              // own slot, own wave region
        float2 a0 = *(const float2*)(p + 0);
        float2 a1 = *(const float2*)(p + 2);
        float2 a2 = *(const float2*)(p + 4);
        float2 a3 = *(const float2*)(p + 6);
        float2 a4 = *(const float2*)(p + 8);
        float x0 = a0.x, x1 = a0.y, x2 = a1.x, x3 = a1.y, x4 = a2.x;
        float x5 = a2.y, x6 = a3.x, x7 = a3.y, x8 = a4.x, x9 = a4.y;
        float m = fmaxf(x0, x1);
        m = fmaxf(m, x2); m = fmaxf(m, x3); m = fmaxf(m, x4);
        m = fmaxf(m, x5); m = fmaxf(m, x6); m = fmaxf(m, x7);
        m = fmaxf(m, x8); m = fmaxf(m, x9);
        float e0v = __expf((x0 - m) * 100.0f);
        float e1v = __expf((x1 - m) * 100.0f);
        float e2v = __expf((x2 - m) * 100.0f);
        float e3v = __expf((x3 - m) * 100.0f);
        float e4v = __expf((x4 - m) * 100.0f);
        float e5v = __expf((x5 - m) * 100.0f);
        float e6v = __expf((x6 - m) * 100.0f);
        float e7v = __expf((x7 - m) * 100.0f);
        float e8v = __expf((x8 - m) * 100.0f);
        float e9v = __expf((x9 - m) * 100.0f);
        float den = e0v + e1v + e2v + e3v + e4v + e5v + e6v + e7v + e8v + e9v;
        float num = e1v + e2v * 2.0f + e3v * 3.0f + e4v * 4.0f +
                    e5v * 5.0f + e6v * 6.0f + e7v * 7.0f + e8v * 8.0f + e9v * 9.0f;
        float contrib = (num / den) * powv;

        // 8 consecutive lanes hold the 8 digit positions of one (elem,node)
        contrib += __shfl_xor(contrib, 1);
        contrib += __shfl_xor(contrib, 2);
        contrib += __shfl_xor(contrib, 4);
        if (dpos == 0) {
            int en = (c * 256 + tid) >> 3;            // el*9 + node
            int el = en / 9, node = en - el * 9;
            s_init[el * 9 + node] = contrib;
        }

        if (c < 8) {                                  // overwrite own region (in-order DS)
            *(float4*)(lb + lane * 4)       = n0;
            *(float4*)(lb + 256 + lane * 4) = n1;
            *(float2*)(lb + 512 + lane * 2) = n2;
        }
    }

    __syncthreads();    // drains vmcnt(0)+lgkmcnt(0): O gl_lds + all LDS writes visible

    // ---- phase 2: DAG, one thread per element ----
    if (tid < EPB) {
        float vmag[NT], sgn[NT], logm[NT], sv[NT];
        #pragma unroll
        for (int n = 0; n < NI; ++n) {
            float v = s_init[tid * 9 + n];
            v = fminf(fmaxf(v, MAG_MIN), MAG_MAX);
            vmag[n] = v;
            sgn[n]  = s_vs[tid * NT + n];
            logm[n] = logf(v);
            sv[n]   = sgn[n] * v;
        }
        #pragma unroll
        for (int n = NI; n < NT; ++n) {
            vmag[n] = 0.0f; sgn[n] = 0.0f;
            logm[n] = logf(MAG_MIN);
            sv[n]   = 0.0f;
        }

        #pragma unroll
        for (int step = 0; step < DEPTH; ++step) {
            const int valid = NI + step;
            float g  = s_G[tid * 9 + step];
            float og = 1.0f - g;
            float R = 0.0f;
            float prod = 1.0f;
            #pragma unroll
            for (int n = 0; n < NT; ++n) {
                if (n < valid) {
                    float o = s_O[tid * 136 + step * 17 + n];
                    float mixed = logm[n] * og + sv[n] * g;
                    R += o * mixed;
                    float wgt = sgn[n] * fabsf(o) * 2.0f + 1.0f;
                    prod *= wgt;
                }
            }
            float linear_sign = tanh_fast(R * 10000.0f);
            float log_sign    = tanh_fast(prod * 10000.0f);
            float s_new = g * linear_sign + og * log_sign;
            float linear_mag  = fminf(fabsf(R), MAG_MAX);
            float Rc = fminf(fmaxf(R, -LOG_LIM), LOG_LIM);
            float log_mag_res = expf(Rc);
            float m_new = g * linear_mag + og * log_mag_res;
            m_new = fminf(fmaxf(m_new, MAG_MIN), MAG_MAX);
            s_new = fminf(fmaxf(s_new, -1.0f), 1.0f);
            vmag[valid] = m_new;
            sgn[valid]  = s_new;
            logm[valid] = logf(m_new);
            sv[valid]   = s_new * m_new;
        }
        out[e0 + tid] = sgn[NT - 1] * vmag[NT - 1];
    }
}

extern "C" void kernel_launch(void* const* d_in, const int* in_sizes, int n_in,
                              void* d_out, int out_size, void* d_ws, size_t ws_size,
                              hipStream_t stream) {
    const float* dl  = (const float*)d_in[0];   // digit_logits [B,T,9,8,10]
    const float* vsg = (const float*)d_in[1];   // V_sign       [B,T,17]
    const float* Og  = (const float*)d_in[2];   // O            [B,T,8,17]
    const float* Gg  = (const float*)d_in[3];   // G            [B,T,8]
    float* out = (float*)d_out;

    const int ne = out_size;                    // 32768
    const int blocks = ne / EPB;                // 1024
    dag_exec_kernel<<<blocks, THREADS, 0, stream>>>(dl, vsg, Og, Gg, out);
}